// Round 7
// baseline (13564.702 us; speedup 1.0000x reference)
//
#include <hip/hip_runtime.h>

// Problem constants
#define Tt    1024
#define INF   256
#define Hh    768
#define OUTF  128

// UNIFIED design: 48 WGs each compute L0(s) AND L1(s-1) for their 16 j-cols
// (both consume the same hA(s-1) broadcast -> staged ONCE, polled ONCE).
// +2 LIN WGs. 50 lines total. One flag per WG per step. 5 barriers/iter.
// All index maps are R0-proven; biases folded into ks==0 accumulators.
#define NWG_U   48
#define NWG_LIN 2
#define NWG     (NWG_U + NWG_LIN)   // 50
#define NTHR    1024
#define NIT     (Tt + 2)            // 1026

typedef unsigned int       u32;
typedef unsigned short     u16;
typedef __attribute__((ext_vector_type(8))) short bf16x8;   // 8 bf16 = 4 VGPRs
typedef __attribute__((ext_vector_type(4))) float f32x4;    // MFMA C/D

// ws layout (bytes). prog[wg]: PRIVATE 128-B line, 1 writer, pollers read.
// h rings: [3 par][32 rows][768 j] bf16 per layer.
#define PROG_OFF 0
#define HPS      24576
#define HA_OFF   16384
#define HB_OFF   (HA_OFF + 3 * 49152)         // 163840
#define WS_BYTES (HB_OFF + 3 * 49152)         // 311296

// LDS (dynamic).
// Unified act: [x 512B | hA 1536B | hB 1536B | pad 16] per row -> stride 3600.
#define ASTU   3600
#define ACTU_B (32 * ASTU)                    // 115200
#define AST2   1552                           // LIN act stride (768 cols, R0)
#define ACT2_B (32 * AST2)                    // 49664
#define RSLAB  272        // red slab stride (dw), R0-proven
#define RROW   17         // red col stride (dw)
#define RED_B  (32 * RSLAB * 4)               // 34816
#define LDS_B  (ACTU_B + RED_B)               // 150016
// Unified: redA @ ACTU_B (L0); redB @ 0 aliases act, written only after B3
// (act dead). LIN: act @ 0 (49664) + redL @ ACT2_B.

__device__ __forceinline__ float sigf(float v){ return 1.0f/(1.0f+__expf(-v)); }
__device__ __forceinline__ float tanhfast(float x){
    const float cx = fminf(fmaxf(x, -15.f), 15.f);
    const float e  = __expf(2.f * cx);
    return (e - 1.f) / (e + 1.f);
}
__device__ __forceinline__ u16 f2bf(float f){           // round-nearest-even
    u32 u = __float_as_uint(f);
    return (u16)((u + 0x7fffu + ((u>>16)&1u)) >> 16);
}
// LLC-coherent accesses for cross-WG data.
__device__ __forceinline__ void st32ws(u16* p, u32 v){
    __hip_atomic_store((u32*)p, v, __ATOMIC_RELAXED, __HIP_MEMORY_SCOPE_AGENT);
}
__device__ __forceinline__ u32 ldu32(const u32* p){
    return __hip_atomic_load(p, __ATOMIC_RELAXED, __HIP_MEMORY_SCOPE_AGENT);
}
__device__ __forceinline__ void stu32(u32* p, u32 v){
    __hip_atomic_store(p, v, __ATOMIC_RELAXED, __HIP_MEMORY_SCOPE_AGENT);
}
// Batched cache-bypassing loads: loads + vmcnt(0) inside ONE asm block
// (outputs never visible to regalloc before the drain — R5 lesson).
__device__ __forceinline__ void ld16x3(const u16* p0, const u16* p1, const u16* p2,
                                       f32x4& r0, f32x4& r1, f32x4& r2){
    asm volatile(
        "global_load_dwordx4 %0, %3, off sc0 sc1\n\t"
        "global_load_dwordx4 %1, %4, off sc0 sc1\n\t"
        "global_load_dwordx4 %2, %5, off sc0 sc1\n\t"
        "s_waitcnt vmcnt(0)"
        : "=&v"(r0), "=&v"(r1), "=&v"(r2)
        : "v"(p0), "v"(p1), "v"(p2)
        : "memory");
}

__global__ void prologue(char* ws){
    int i = blockIdx.x * 256 + threadIdx.x;
    if (i < WS_BYTES / 4)
        __hip_atomic_store(((u32*)ws) + i, 0u, __ATOMIC_RELAXED, __HIP_MEMORY_SCOPE_AGENT);
}

__device__ __forceinline__ bf16x8 load8w(const float* p){
    float4 v0 = *(const float4*)(p);
    float4 v1 = *(const float4*)(p + 4);
    bf16x8 r;
    r[0]=(short)f2bf(v0.x); r[1]=(short)f2bf(v0.y); r[2]=(short)f2bf(v0.z); r[3]=(short)f2bf(v0.w);
    r[4]=(short)f2bf(v1.x); r[5]=(short)f2bf(v1.y); r[6]=(short)f2bf(v1.z); r[7]=(short)f2bf(v1.w);
    return r;
}

__global__ __launch_bounds__(NTHR) void lstm_persist(
    const float* __restrict__ x,
    const float* __restrict__ Wih0, const float* __restrict__ Whh0,
    const float* __restrict__ bih0, const float* __restrict__ bhh0,
    const float* __restrict__ Wih1, const float* __restrict__ Whh1,
    const float* __restrict__ bih1, const float* __restrict__ bhh1,
    const float* __restrict__ Wlin, const float* __restrict__ blin,
    float* __restrict__ out, char* ws)
{
    u32* prog = (u32*)(ws + PROG_OFF);
    u16* hA   = (u16*)(ws + HA_OFF);
    u16* hB   = (u16*)(ws + HB_OFF);

    const int wg  = blockIdx.x;
    const int tid = threadIdx.x;

    extern __shared__ __align__(16) char smem[];

    const int lane = tid & 63, w = tid >> 6;
    const int quad = lane >> 4, nl = lane & 15;
    const int nt = w >> 2, ks = w & 3;          // gate/out tile, K-slice

    const bool isU  = (wg < NWG_U);
    const int jbase = isU ? wg * 16 : 0;
    const int obase = isU ? 0 : (wg - NWG_U) * 64;

    char*  actb = smem;
    float* redA = (float*)(smem + ACTU_B);   // unified L0 red
    float* redB = (float*)(smem);            // unified L1 red (post-B3 only)
    float* redL = (float*)(smem + ACT2_B);   // LIN red

    // ---- register-resident bf16 weights (B-frags): n = lane&15, k = quad*8+j ----
    bf16x8 bfrX[8];    // unified L0: K = [x(256); hA(768)]  (R0-L0 map)
    bf16x8 bfr[12];    // unified L1: K = [hA; hB] (R0-L1 map) / LIN: first 6
    float biasA = 0.f, biasB = 0.f;
    if (isU) {
        const int grow = nt * Hh + jbase + nl;
        #pragma unroll
        for (int fi = 0; fi < 8; ++fi) {
            const int ka = ks * 256 + fi * 32 + quad * 8;
            const float* p = (ka < 256) ? (Wih0 + (size_t)grow * 256 + ka)
                                        : (Whh0 + (size_t)grow * 768 + (ka - 256));
            bfrX[fi] = load8w(p);
        }
        #pragma unroll
        for (int fi = 0; fi < 12; ++fi) {
            const int ka = ks * 384 + fi * 32 + quad * 8;
            const float* p = (ka < 768) ? (Wih1 + (size_t)grow * 768 + ka)
                                        : (Whh1 + (size_t)grow * 768 + (ka - 768));
            bfr[fi] = load8w(p);
        }
        biasA = bih0[grow] + bhh0[grow];   // bias per n-col (gate nt, col jbase+nl)
        biasB = bih1[grow] + bhh1[grow];
    } else {
        const int row = obase + nt * 16 + nl;
        #pragma unroll
        for (int fi = 0; fi < 6; ++fi) {
            const int ka = ks * 192 + fi * 32 + quad * 8;
            bfr[fi] = load8w(Wlin + (size_t)row * 768 + ka);
        }
    }

    // cell state (gate threads tid<256): j-pair {jbase+2jj, +1}, row b2
    float cA0 = 0.f, cA1 = 0.f, cB0 = 0.f, cB1 = 0.f;
    float bl0 = 0.f, bl1 = 0.f;
    if (!isU) {
        bl0 = blin[obase + (tid >> 5)];
        bl1 = blin[obase + 32 + (tid >> 5)];
    }

    for (int s = 0; s < NIT; ++s) {
        const int par_wA = s % 3;              // hA(s)
        const int par_rA = (s + 2) % 3;        // hA(s-1)
        const int par_wB = (s + 2) % 3;        // hB(s-1)
        const int par_rB = (s + 1) % 3;        // hB(s-2)

        if (isU) {
            if (s > Tt) continue;              // uniform per WG
            // ---- poll: lines 0-47 >= s (hA(s-1) & hB(s-2)); LIN >= s-1 (WAR) ----
            if (w == 0) {
                int idx = -1; u32 thr = 0;
                if (lane < 48)      { idx = lane; thr = (u32)s; }
                else if (lane < 50) { idx = lane; thr = (s >= 4) ? (u32)(s - 1) : 0u; }
                bool ok = (idx < 0);
                int guard = 0;
                while (guard < (1 << 24)) {
                    if (!ok) ok = (ldu32(prog + idx * 32) >= thr);
                    if (__ballot(ok) == ~0ull) break;
                    __builtin_amdgcn_s_sleep(1); ++guard;
                }
            }
            __syncthreads();   // B1

            // ---- stage x(s) (cols [0,512)B) ----
            if (s < Tt) {
                const int xr = tid >> 5, q = tid & 31;
                const float* xs = x + ((size_t)xr * Tt + s) * INF + q * 8;
                const float4 v0 = ((const float4*)xs)[0];
                const float4 v1 = ((const float4*)xs)[1];
                uint4 a;
                a.x = (u32)f2bf(v0.x) | ((u32)f2bf(v0.y) << 16);
                a.y = (u32)f2bf(v0.z) | ((u32)f2bf(v0.w) << 16);
                a.z = (u32)f2bf(v1.x) | ((u32)f2bf(v1.y) << 16);
                a.w = (u32)f2bf(v1.z) | ((u32)f2bf(v1.w) << 16);
                *(uint4*)(actb + xr * ASTU + q * 16) = a;
            }
            // ---- stage hA(s-1)+hB(s-2): 6144 chunks, 6/thread, 2x ld16x3 ----
            {
                const u16* pA = hA + (size_t)par_rA * HPS;
                const u16* pB = hB + (size_t)par_rB * HPS;
                #pragma unroll
                for (int b = 0; b < 2; ++b) {
                    const u16* pp[3]; u32 la[3];
                    #pragma unroll
                    for (int u = 0; u < 3; ++u) {
                        const int G = (b * 3 + u) * 1024 + tid;
                        const int row = G / 192, c = G - row * 192;
                        la[u] = (u32)(row * ASTU + 512 + c * 16);
                        pp[u] = (c < 96) ? (pA + (size_t)row * 768 + (size_t)c * 8)
                                         : (pB + (size_t)row * 768 + (size_t)(c - 96) * 8);
                    }
                    f32x4 h0, h1, h2;
                    ld16x3(pp[0], pp[1], pp[2], h0, h1, h2);
                    *(f32x4*)(actb + la[0]) = h0;
                    *(f32x4*)(actb + la[1]) = h1;
                    *(f32x4*)(actb + la[2]) = h2;
                }
            }
            __syncthreads();   // B2: act ready

            // ---- MFMA both layers (bias folded in at ks==0) ----
            f32x4 accA0 = {0,0,0,0}, accA1 = {0,0,0,0};
            f32x4 accB0 = {0,0,0,0}, accB1 = {0,0,0,0};
            if (s < Tt) {
                #pragma unroll
                for (int fc = 0; fc < 8; ++fc) {
                    const int kb = (ks * 256 + fc * 32 + quad * 8) * 2;
                    bf16x8 a0 = *(const bf16x8*)(actb + nl * ASTU + kb);
                    bf16x8 a1 = *(const bf16x8*)(actb + (16 + nl) * ASTU + kb);
                    accA0 = __builtin_amdgcn_mfma_f32_16x16x32_bf16(a0, bfrX[fc], accA0, 0, 0, 0);
                    accA1 = __builtin_amdgcn_mfma_f32_16x16x32_bf16(a1, bfrX[fc], accA1, 0, 0, 0);
                }
                if (ks == 0) {
                    const f32x4 bv = {biasA, biasA, biasA, biasA};
                    accA0 += bv; accA1 += bv;
                }
            }
            if (s >= 1) {
                #pragma unroll
                for (int fc = 0; fc < 12; ++fc) {
                    const int kb = 512 + (ks * 384 + fc * 32 + quad * 8) * 2;
                    bf16x8 a0 = *(const bf16x8*)(actb + nl * ASTU + kb);
                    bf16x8 a1 = *(const bf16x8*)(actb + (16 + nl) * ASTU + kb);
                    accB0 = __builtin_amdgcn_mfma_f32_16x16x32_bf16(a0, bfr[fc], accB0, 0, 0, 0);
                    accB1 = __builtin_amdgcn_mfma_f32_16x16x32_bf16(a1, bfr[fc], accB1, 0, 0, 0);
                }
                if (ks == 0) {
                    const f32x4 bv = {biasB, biasB, biasB, biasB};
                    accB0 += bv; accB1 += bv;
                }
            }
            // D layout: col n = lane&15, row m = quad*4 + reg.
            if (s < Tt) {
                *(f32x4*)&redA[(size_t)((nt * 2 + 0) * 4 + ks) * RSLAB + nl * RROW + quad * 4] = accA0;
                *(f32x4*)&redA[(size_t)((nt * 2 + 1) * 4 + ks) * RSLAB + nl * RROW + quad * 4] = accA1;
            }
            __syncthreads();   // B3: redA ready; act dead -> redB usable

            if (s >= 1) {
                *(f32x4*)&redB[(size_t)((nt * 2 + 0) * 4 + ks) * RSLAB + nl * RROW + quad * 4] = accB0;
                *(f32x4*)&redB[(size_t)((nt * 2 + 1) * 4 + ks) * RSLAB + nl * RROW + quad * 4] = accB1;
            }
            if (s < Tt && tid < 256) {
                // ---- L0 gates: reduce redA + gates + packed hA store ----
                const int jj = tid >> 5, b2 = tid & 31;
                const int mt = b2 >> 4, mr = b2 & 15;
                const int j0 = 2 * jj, j1 = j0 + 1;
                float p0a=0,p1a=0,p2a=0,p3a=0, p0b=0,p1b=0,p2b=0,p3b=0;
                #pragma unroll
                for (int k2 = 0; k2 < 4; ++k2) {
                    p0a += redA[(size_t)((0 * 2 + mt) * 4 + k2) * RSLAB + j0 * RROW + mr];
                    p1a += redA[(size_t)((1 * 2 + mt) * 4 + k2) * RSLAB + j0 * RROW + mr];
                    p2a += redA[(size_t)((2 * 2 + mt) * 4 + k2) * RSLAB + j0 * RROW + mr];
                    p3a += redA[(size_t)((3 * 2 + mt) * 4 + k2) * RSLAB + j0 * RROW + mr];
                    p0b += redA[(size_t)((0 * 2 + mt) * 4 + k2) * RSLAB + j1 * RROW + mr];
                    p1b += redA[(size_t)((1 * 2 + mt) * 4 + k2) * RSLAB + j1 * RROW + mr];
                    p2b += redA[(size_t)((2 * 2 + mt) * 4 + k2) * RSLAB + j1 * RROW + mr];
                    p3b += redA[(size_t)((3 * 2 + mt) * 4 + k2) * RSLAB + j1 * RROW + mr];
                }
                const float ig0 = sigf(p0a), fg0 = sigf(p1a);
                const float gv0 = tanhfast(p2a), og0 = sigf(p3a);
                cA0 = fg0 * cA0 + ig0 * gv0;
                const float h0 = og0 * tanhfast(cA0);
                const float ig1 = sigf(p0b), fg1 = sigf(p1b);
                const float gv1 = tanhfast(p2b), og1 = sigf(p3b);
                cA1 = fg1 * cA1 + ig1 * gv1;
                const float h1 = og1 * tanhfast(cA1);
                st32ws(hA + (size_t)par_wA * HPS + b2 * 768 + jbase + j0,
                       (u32)f2bf(h0) | ((u32)f2bf(h1) << 16));
            }
            __syncthreads();   // B4: redB ready; L0 gates done

            if (s >= 1 && tid < 256) {
                // ---- L1 gates: reduce redB + gates + packed hB store ----
                const int jj = tid >> 5, b2 = tid & 31;
                const int mt = b2 >> 4, mr = b2 & 15;
                const int j0 = 2 * jj, j1 = j0 + 1;
                float p0a=0,p1a=0,p2a=0,p3a=0, p0b=0,p1b=0,p2b=0,p3b=0;
                #pragma unroll
                for (int k2 = 0; k2 < 4; ++k2) {
                    p0a += redB[(size_t)((0 * 2 + mt) * 4 + k2) * RSLAB + j0 * RROW + mr];
                    p1a += redB[(size_t)((1 * 2 + mt) * 4 + k2) * RSLAB + j0 * RROW + mr];
                    p2a += redB[(size_t)((2 * 2 + mt) * 4 + k2) * RSLAB + j0 * RROW + mr];
                    p3a += redB[(size_t)((3 * 2 + mt) * 4 + k2) * RSLAB + j0 * RROW + mr];
                    p0b += redB[(size_t)((0 * 2 + mt) * 4 + k2) * RSLAB + j1 * RROW + mr];
                    p1b += redB[(size_t)((1 * 2 + mt) * 4 + k2) * RSLAB + j1 * RROW + mr];
                    p2b += redB[(size_t)((2 * 2 + mt) * 4 + k2) * RSLAB + j1 * RROW + mr];
                    p3b += redB[(size_t)((3 * 2 + mt) * 4 + k2) * RSLAB + j1 * RROW + mr];
                }
                const float ig0 = sigf(p0a), fg0 = sigf(p1a);
                const float gv0 = tanhfast(p2a), og0 = sigf(p3a);
                cB0 = fg0 * cB0 + ig0 * gv0;
                const float h0 = og0 * tanhfast(cB0);
                const float ig1 = sigf(p0b), fg1 = sigf(p1b);
                const float gv1 = tanhfast(p2b), og1 = sigf(p3b);
                cB1 = fg1 * cB1 + ig1 * gv1;
                const float h1 = og1 * tanhfast(cB1);
                st32ws(hB + (size_t)par_wB * HPS + b2 * 768 + jbase + j0,
                       (u32)f2bf(h0) | ((u32)f2bf(h1) << 16));
            }
            __syncthreads();   // B5: all h stores drained (per-wave vmcnt at barrier)
            if (tid == 0) stu32(prog + wg * 32, (u32)(s + 1));
        } else {
            // ---- LIN: out(s-2) from hB(s-2) ----
            if (s < 2) continue;
            if (w == 0) {
                const int idx = (lane < 48) ? lane : -1;
                bool ok = (idx < 0);
                int guard = 0;
                while (guard < (1 << 24)) {
                    if (!ok) ok = (ldu32(prog + idx * 32) >= (u32)s);
                    if (__ballot(ok) == ~0ull) break;
                    __builtin_amdgcn_s_sleep(1); ++guard;
                }
            }
            __syncthreads();   // B1
            {
                const u16* pB = hB + (size_t)par_rB * HPS;
                const int r0 = tid / 96,  c0 = tid - r0 * 96;
                const int G1 = 1024 + tid, r1 = G1 / 96, c1 = G1 - r1 * 96;
                const int G2 = 2048 + tid, r2 = G2 / 96, c2 = G2 - r2 * 96;
                f32x4 h0, h1, h2;
                ld16x3(pB + (size_t)r0 * 768 + c0 * 8,
                       pB + (size_t)r1 * 768 + c1 * 8,
                       pB + (size_t)r2 * 768 + c2 * 8, h0, h1, h2);
                *(f32x4*)(actb + r0 * AST2 + c0 * 16) = h0;
                *(f32x4*)(actb + r1 * AST2 + c1 * 16) = h1;
                *(f32x4*)(actb + r2 * AST2 + c2 * 16) = h2;
            }
            __syncthreads();   // B2: act ready; hB reads done -> release WAR
            if (tid == 0) stu32(prog + wg * 32, (u32)(s + 1));

            f32x4 acc0 = {0,0,0,0}, acc1 = {0,0,0,0};
            #pragma unroll
            for (int fc = 0; fc < 6; ++fc) {
                const int kb = (ks * 192 + fc * 32 + quad * 8) * 2;
                bf16x8 a0 = *(const bf16x8*)(actb + nl * AST2 + kb);
                bf16x8 a1 = *(const bf16x8*)(actb + (16 + nl) * AST2 + kb);
                acc0 = __builtin_amdgcn_mfma_f32_16x16x32_bf16(a0, bfr[fc], acc0, 0, 0, 0);
                acc1 = __builtin_amdgcn_mfma_f32_16x16x32_bf16(a1, bfr[fc], acc1, 0, 0, 0);
            }
            *(f32x4*)&redL[(size_t)((nt * 2 + 0) * 4 + ks) * RSLAB + nl * RROW + quad * 4] = acc0;
            *(f32x4*)&redL[(size_t)((nt * 2 + 1) * 4 + ks) * RSLAB + nl * RROW + quad * 4] = acc1;
            __syncthreads();   // B3: red ready

            const int v = s - 2;
            const int r2o = tid >> 5, bb = tid & 31;
            const int mtr = bb >> 4, mr2 = bb & 15;
            const int nt0 = r2o >> 4, nr0 = r2o & 15;
            const int nt1 = (r2o + 32) >> 4, nr1 = (r2o + 32) & 15;
            float s0 = 0.f, s1 = 0.f;
            #pragma unroll
            for (int k2 = 0; k2 < 4; ++k2) {
                s0 += redL[(size_t)((nt0 * 2 + mtr) * 4 + k2) * RSLAB + nr0 * RROW + mr2];
                s1 += redL[(size_t)((nt1 * 2 + mtr) * 4 + k2) * RSLAB + nr1 * RROW + mr2];
            }
            float* o = out + ((size_t)bb * Tt + v) * OUTF + obase;
            o[r2o]      = s0 + bl0;
            o[32 + r2o] = s1 + bl1;
        }
    }
}

extern "C" void kernel_launch(void* const* d_in, const int* in_sizes, int n_in,
                              void* d_out, int out_size, void* d_ws, size_t ws_size,
                              hipStream_t stream)
{
    const float* x    = (const float*)d_in[0];
    const float* Wih0 = (const float*)d_in[1];
    const float* Whh0 = (const float*)d_in[2];
    const float* bih0 = (const float*)d_in[3];
    const float* bhh0 = (const float*)d_in[4];
    const float* Wih1 = (const float*)d_in[5];
    const float* Whh1 = (const float*)d_in[6];
    const float* bih1 = (const float*)d_in[7];
    const float* bhh1 = (const float*)d_in[8];
    const float* Wlin = (const float*)d_in[9];
    const float* blin = (const float*)d_in[10];
    float* out = (float*)d_out;
    char*  ws  = (char*)d_ws;   // uses WS_BYTES = 311296 B

    static bool attr_done = false;
    if (!attr_done) {
        hipFuncSetAttribute((const void*)lstm_persist,
                            hipFuncAttributeMaxDynamicSharedMemorySize, 160 * 1024);
        attr_done = true;
    }

    hipLaunchKernelGGL(prologue, dim3(304), dim3(256), 0, stream, ws);
    hipLaunchKernelGGL(lstm_persist, dim3(NWG), dim3(NTHR), LDS_B, stream,
                       x, Wih0, Whh0, bih0, bhh0,
                       Wih1, Whh1, bih1, bhh1,
                       Wlin, blin, out, ws);
}

// Round 9
// 6174.508 us; speedup vs baseline: 2.1969x; 2.1969x over previous
//
#include <hip/hip_runtime.h>

// Problem constants
#define Tt    1024
#define INF   256
#define Hh    768
#define OUTF  128

// R9 = R0 (proven 6240us) with exactly two changes:
//  1. BUSY-POLL: s_sleep removed from poll loops (anti-DVFS: keep clocks up,
//     sharpen detect). R1 proved the period is not dependency latency; the
//     ~2.5x gap between cycle model and wall clock points at clock droop.
//  2. LIN publishes its WAR flag right after its hB reads drain (early release).
// Grid: 48 L0 + 48 L1 + 2 LIN WGs, 1024 thr each.
#define NWG_L0  48
#define NWG_L1  48
#define NWG_LIN 2
#define NWG     (NWG_L0 + NWG_L1 + NWG_LIN)   // 98
#define NTHR    1024

typedef unsigned int       u32;
typedef unsigned long long u64;
typedef unsigned short     u16;
typedef __attribute__((ext_vector_type(8))) short bf16x8;   // 8 bf16 = 4 VGPRs
typedef __attribute__((ext_vector_type(4))) float f32x4;    // MFMA C/D

// ws layout (bytes). prog[wg]: PRIVATE 128-B line, 1 writer, N pollers.
#define PROG_OFF 0                    // 98 lines x 128 B
#define HA_OFF   16384                // hA ring: [3 parity][32 b][768 j] bf16
#define HB_OFF   (HA_OFF + 3*49152)   // hB ring: same
#define WS_BYTES (HB_OFF + 3*49152)   // 311,296 B
#define HPS      24576                // parity stride in u16 (32*768)

#define ASTR_B 1552        // act LDS row stride bytes (776 bf16)
#define RSLAB  272         // red slab stride (dw)
#define RROW   17          // red row stride (dw)

__device__ __forceinline__ float sigf(float v){ return 1.0f/(1.0f+__expf(-v)); }
__device__ __forceinline__ float tanhfast(float x){
    const float cx = fminf(fmaxf(x, -15.f), 15.f);
    const float e  = __expf(2.f * cx);
    return (e - 1.f) / (e + 1.f);
}
__device__ __forceinline__ u16 f2bf(float f){           // round-nearest-even
    u32 u = __float_as_uint(f);
    return (u16)((u + 0x7fffu + ((u>>16)&1u)) >> 16);
}
// LLC-coherent (L1/L2-bypassing) accesses for cross-WG data.
__device__ __forceinline__ void st32ws(u16* p, u32 v){
    __hip_atomic_store((u32*)p, v, __ATOMIC_RELAXED, __HIP_MEMORY_SCOPE_AGENT);
}
__device__ __forceinline__ u32 ldu32(const u32* p){
    return __hip_atomic_load(p, __ATOMIC_RELAXED, __HIP_MEMORY_SCOPE_AGENT);
}
__device__ __forceinline__ void stu32(u32* p, u32 v){
    __hip_atomic_store(p, v, __ATOMIC_RELAXED, __HIP_MEMORY_SCOPE_AGENT);
}
// 16-B cache-bypassing loads, batched, single vmcnt drain inside ONE asm block.
__device__ __forceinline__ void ld16x3(const u16* p0, const u16* p1, const u16* p2,
                                       f32x4& r0, f32x4& r1, f32x4& r2){
    asm volatile(
        "global_load_dwordx4 %0, %3, off sc0 sc1\n\t"
        "global_load_dwordx4 %1, %4, off sc0 sc1\n\t"
        "global_load_dwordx4 %2, %5, off sc0 sc1\n\t"
        "s_waitcnt vmcnt(0)"
        : "=&v"(r0), "=&v"(r1), "=&v"(r2)
        : "v"(p0), "v"(p1), "v"(p2)
        : "memory");
}
__device__ __forceinline__ void ld16x6(const u16* p0, const u16* p1, const u16* p2,
                                       const u16* p3, const u16* p4, const u16* p5,
                                       f32x4& r0, f32x4& r1, f32x4& r2,
                                       f32x4& r3, f32x4& r4, f32x4& r5){
    asm volatile(
        "global_load_dwordx4 %0, %6, off sc0 sc1\n\t"
        "global_load_dwordx4 %1, %7, off sc0 sc1\n\t"
        "global_load_dwordx4 %2, %8, off sc0 sc1\n\t"
        "global_load_dwordx4 %3, %9, off sc0 sc1\n\t"
        "global_load_dwordx4 %4, %10, off sc0 sc1\n\t"
        "global_load_dwordx4 %5, %11, off sc0 sc1\n\t"
        "s_waitcnt vmcnt(0)"
        : "=&v"(r0), "=&v"(r1), "=&v"(r2), "=&v"(r3), "=&v"(r4), "=&v"(r5)
        : "v"(p0), "v"(p1), "v"(p2), "v"(p3), "v"(p4), "v"(p5)
        : "memory");
}

// Gang-poll cnt lines [base, base+cnt) for prog >= thr. Wave 0 only. BUSY.
__device__ __forceinline__ void waitlines(u32* prog, int base, int cnt, u32 thr, int lane){
    bool ok = (lane >= cnt);
    int guard = 0;
    while (guard < (1 << 24)) {
        if (!ok) ok = (ldu32(prog + (base + lane) * 32) >= thr);
        if (__ballot(ok) == ~0ull) break;
        ++guard;
    }
}

__global__ void prologue(char* ws){
    int i = blockIdx.x * 256 + threadIdx.x;
    if (i < WS_BYTES / 4)
        __hip_atomic_store(((u32*)ws) + i, 0u, __ATOMIC_RELAXED, __HIP_MEMORY_SCOPE_AGENT);
}

__device__ __forceinline__ bf16x8 load8w(const float* p){
    float4 v0 = *(const float4*)(p);
    float4 v1 = *(const float4*)(p + 4);
    bf16x8 r;
    r[0]=(short)f2bf(v0.x); r[1]=(short)f2bf(v0.y); r[2]=(short)f2bf(v0.z); r[3]=(short)f2bf(v0.w);
    r[4]=(short)f2bf(v1.x); r[5]=(short)f2bf(v1.y); r[6]=(short)f2bf(v1.z); r[7]=(short)f2bf(v1.w);
    return r;
}

__global__ __launch_bounds__(NTHR) void lstm_persist(
    const float* __restrict__ x,
    const float* __restrict__ Wih0, const float* __restrict__ Whh0,
    const float* __restrict__ bih0, const float* __restrict__ bhh0,
    const float* __restrict__ Wih1, const float* __restrict__ Whh1,
    const float* __restrict__ bih1, const float* __restrict__ bhh1,
    const float* __restrict__ Wlin, const float* __restrict__ blin,
    float* __restrict__ out, char* ws)
{
    u32* prog = (u32*)(ws + PROG_OFF);
    u16* hA   = (u16*)(ws + HA_OFF);
    u16* hB   = (u16*)(ws + HB_OFF);

    const int wg  = blockIdx.x;
    const int tid = threadIdx.x;

    __shared__ __align__(16) char smem[49664];
    char*  actb = smem;                 // [32 b][776 bf16] staging (per chunk)
    float* red  = (float*)smem;         // padded slabs; aliases act after MFMAs

    const int lane = tid & 63, w = tid >> 6;
    const int quad = lane >> 4, nl = lane & 15;
    const int nt = w >> 2, ks = w & 3;          // n-tile 0..3, K-slice 0..3
    const int b3 = tid >> 5, q = tid & 31;      // staging map: batch row, col-block

    const int role  = (wg < NWG_L0) ? 0 : ((wg < NWG_L0 + NWG_L1) ? 1 : 2);
    const int jbase = (role == 0) ? wg * 16 : ((role == 1) ? (wg - NWG_L0) * 16 : 0);
    const int obase = (role == 2) ? (wg - NWG_L0 - NWG_L1) * 64 : 0;

    // ---- register-resident bf16 weights (B-frags), loaded ONCE ----
    // B-frag layout: n = lane&15, k = quad*8 + j.
    bf16x8 bfr[12];
    if (role == 0) {
        const int grow = nt * Hh + jbase + nl;
        #pragma unroll
        for (int fi = 0; fi < 8; ++fi) {
            const int c = fi >> 2, fc = fi & 3;
            const int ka = c * 512 + ks * 128 + fc * 32 + quad * 8;   // K: [x(256); hA(768)]
            const float* p = (ka < 256) ? (Wih0 + (size_t)grow * 256 + ka)
                                        : (Whh0 + (size_t)grow * 768 + (ka - 256));
            bfr[fi] = load8w(p);
        }
    } else if (role == 1) {
        const int grow = nt * Hh + jbase + nl;
        #pragma unroll
        for (int fi = 0; fi < 12; ++fi) {
            const int c = fi / 6, fc = fi % 6;
            const int ka = c * 768 + ks * 192 + fc * 32 + quad * 8;   // K: [hA; hB]
            const float* p = (ka < 768) ? (Wih1 + (size_t)grow * 768 + ka)
                                        : (Whh1 + (size_t)grow * 768 + (ka - 768));
            bfr[fi] = load8w(p);
        }
    } else {
        const int row = obase + nt * 16 + nl;
        #pragma unroll
        for (int fi = 0; fi < 6; ++fi) {
            const int ka = ks * 192 + fi * 32 + quad * 8;
            bfr[fi] = load8w(Wlin + (size_t)row * 768 + ka);
        }
    }

    // gate-thread constants: tid<256 owns (jj, b2) -> j-pair {2jj, 2jj+1}; c in regs
    float ba0=0,ba1=0,ba2=0,ba3=0, bb0=0,bb1=0,bb2=0,bb3=0, creg0=0, creg1=0;
    float bl0 = 0.f, bl1 = 0.f;
    if (role < 2 && tid < 256) {
        const int jg0 = jbase + 2 * (tid >> 5), jg1 = jg0 + 1;
        const float* bi = (role == 0) ? bih0 : bih1;
        const float* bh = (role == 0) ? bhh0 : bhh1;
        ba0 = bi[jg0]        + bh[jg0];        bb0 = bi[jg1]        + bh[jg1];
        ba1 = bi[768 + jg0]  + bh[768 + jg0];  bb1 = bi[768 + jg1]  + bh[768 + jg1];
        ba2 = bi[1536 + jg0] + bh[1536 + jg0]; bb2 = bi[1536 + jg1] + bh[1536 + jg1];
        ba3 = bi[2304 + jg0] + bh[2304 + jg0]; bb3 = bi[2304 + jg1] + bh[2304 + jg1];
    }
    if (role == 2) {
        bl0 = blin[obase + (tid >> 5)];
        bl1 = blin[obase + 32 + (tid >> 5)];
    }

    for (int s = 0; s < Tt + 2; ++s) {
        const bool active = (role == 0) ? (s < Tt)
                          : (role == 1) ? (s >= 1 && s <= Tt)
                          :               (s >= 2);
        const int par_wA = s % 3;              // hA@s      (L0 write)
        const int par_rA = (s + 2) % 3;        // hA@(s-1)  (L0/L1 read)
        const int par_wB = (s + 2) % 3;        // hB@(s-1)  (L1 write)
        const int par_rB = (s + 1) % 3;        // hB@(s-2)  (L1/LIN read)

        // ---- direct dependency polling (wave 0 gang-polls producer lines) ----
        if (active && w == 0) {
            if (role == 0) {
                if (s >= 1) waitlines(prog, 0, 48, (u32)s, lane);            // own: L0 fin s-1
                if (s >= 2) waitlines(prog, 48, 48, (u32)(s - 1), lane);     // WAR: L1 fin s-2
            } else if (role == 1) {
                waitlines(prog, 48, 48, (u32)s, lane);                       // own: L1 fin s-1
                {   // merged: L0 fin s-1 (lanes 0..47) + LIN fin s-2 (lanes 48..49)
                    const u32 thr2 = (lane < 48) ? (u32)s : (u32)(s - 1);
                    const int idx  = (lane < 48) ? lane : (96 + (lane - 48));
                    bool ok = (lane >= 50);
                    int guard = 0;
                    while (guard < (1 << 24)) {
                        if (!ok) ok = (ldu32(prog + idx * 32) >= thr2);
                        if (__ballot(ok) == ~0ull) break;
                        ++guard;
                    }
                }
            } else {
                waitlines(prog, 48, 48, (u32)s, lane);                       // L1 fin s-1
            }
        }
        __syncthreads();

        if (active) {
            f32x4 acc0 = {0.f,0.f,0.f,0.f}, acc1 = {0.f,0.f,0.f,0.f};

            if (role == 0) {
                const float* xs = x + ((size_t)b3 * Tt + s) * INF + q * 8;
                const float4 v0 = *(const float4*)xs;
                const float4 v1 = *(const float4*)(xs + 4);
                const u16* hp = hA + (size_t)par_rA * HPS + b3 * 768;
                f32x4 h0, h1, h2;
                ld16x3(hp + q * 8, hp + 256 + q * 8, hp + 512 + q * 8, h0, h1, h2);
                // chunk 0: cols [0,256)=x(t) bf16, [256,512)=hA[0,256)
                {
                    uint4 xv;
                    xv.x = (u32)f2bf(v0.x) | ((u32)f2bf(v0.y) << 16);
                    xv.y = (u32)f2bf(v0.z) | ((u32)f2bf(v0.w) << 16);
                    xv.z = (u32)f2bf(v1.x) | ((u32)f2bf(v1.y) << 16);
                    xv.w = (u32)f2bf(v1.z) | ((u32)f2bf(v1.w) << 16);
                    *(uint4*)(actb + b3 * ASTR_B + q * 16) = xv;
                    *(f32x4*)(actb + b3 * ASTR_B + 512 + q * 16) = h0;
                }
                __syncthreads();
                #pragma unroll
                for (int fc = 0; fc < 4; ++fc) {
                    const int koff = ks * 128 + fc * 32 + quad * 8;
                    bf16x8 a0 = *(const bf16x8*)(actb + nl * ASTR_B + koff * 2);
                    bf16x8 a1 = *(const bf16x8*)(actb + (16 + nl) * ASTR_B + koff * 2);
                    acc0 = __builtin_amdgcn_mfma_f32_16x16x32_bf16(a0, bfr[fc], acc0, 0, 0, 0);
                    acc1 = __builtin_amdgcn_mfma_f32_16x16x32_bf16(a1, bfr[fc], acc1, 0, 0, 0);
                }
                __syncthreads();
                // chunk 1: cols [0,512) = hA[256,768)
                *(f32x4*)(actb + b3 * ASTR_B + q * 16)       = h1;
                *(f32x4*)(actb + b3 * ASTR_B + 512 + q * 16) = h2;
                __syncthreads();
                #pragma unroll
                for (int fc = 0; fc < 4; ++fc) {
                    const int koff = ks * 128 + fc * 32 + quad * 8;
                    bf16x8 a0 = *(const bf16x8*)(actb + nl * ASTR_B + koff * 2);
                    bf16x8 a1 = *(const bf16x8*)(actb + (16 + nl) * ASTR_B + koff * 2);
                    acc0 = __builtin_amdgcn_mfma_f32_16x16x32_bf16(a0, bfr[4 + fc], acc0, 0, 0, 0);
                    acc1 = __builtin_amdgcn_mfma_f32_16x16x32_bf16(a1, bfr[4 + fc], acc1, 0, 0, 0);
                }
                __syncthreads();
            } else if (role == 1) {
                const u16* pA = hA + (size_t)par_rA * HPS + b3 * 768;
                const u16* pB = hB + (size_t)par_rB * HPS + b3 * 768;
                f32x4 a0, a1, a2, bq0, bq1, bq2;
                ld16x6(pA + q * 8, pA + 256 + q * 8, pA + 512 + q * 8,
                       pB + q * 8, pB + 256 + q * 8, pB + 512 + q * 8,
                       a0, a1, a2, bq0, bq1, bq2);
                // chunk 0 = hA cols [0,768)
                *(f32x4*)(actb + b3 * ASTR_B + q * 16)        = a0;
                *(f32x4*)(actb + b3 * ASTR_B + 512 + q * 16)  = a1;
                *(f32x4*)(actb + b3 * ASTR_B + 1024 + q * 16) = a2;
                __syncthreads();
                #pragma unroll
                for (int fc = 0; fc < 6; ++fc) {
                    const int koff = ks * 192 + fc * 32 + quad * 8;
                    bf16x8 f0 = *(const bf16x8*)(actb + nl * ASTR_B + koff * 2);
                    bf16x8 f1 = *(const bf16x8*)(actb + (16 + nl) * ASTR_B + koff * 2);
                    acc0 = __builtin_amdgcn_mfma_f32_16x16x32_bf16(f0, bfr[fc], acc0, 0, 0, 0);
                    acc1 = __builtin_amdgcn_mfma_f32_16x16x32_bf16(f1, bfr[fc], acc1, 0, 0, 0);
                }
                __syncthreads();
                // chunk 1 = hB cols [0,768)
                *(f32x4*)(actb + b3 * ASTR_B + q * 16)        = bq0;
                *(f32x4*)(actb + b3 * ASTR_B + 512 + q * 16)  = bq1;
                *(f32x4*)(actb + b3 * ASTR_B + 1024 + q * 16) = bq2;
                __syncthreads();
                #pragma unroll
                for (int fc = 0; fc < 6; ++fc) {
                    const int koff = ks * 192 + fc * 32 + quad * 8;
                    bf16x8 f0 = *(const bf16x8*)(actb + nl * ASTR_B + koff * 2);
                    bf16x8 f1 = *(const bf16x8*)(actb + (16 + nl) * ASTR_B + koff * 2);
                    acc0 = __builtin_amdgcn_mfma_f32_16x16x32_bf16(f0, bfr[6 + fc], acc0, 0, 0, 0);
                    acc1 = __builtin_amdgcn_mfma_f32_16x16x32_bf16(f1, bfr[6 + fc], acc1, 0, 0, 0);
                }
                __syncthreads();
            } else {
                const u16* pB = hB + (size_t)par_rB * HPS + b3 * 768;
                f32x4 bq0, bq1, bq2;
                ld16x3(pB + q * 8, pB + 256 + q * 8, pB + 512 + q * 8, bq0, bq1, bq2);
                *(f32x4*)(actb + b3 * ASTR_B + q * 16)        = bq0;
                *(f32x4*)(actb + b3 * ASTR_B + 512 + q * 16)  = bq1;
                *(f32x4*)(actb + b3 * ASTR_B + 1024 + q * 16) = bq2;
                __syncthreads();
                // R9: early WAR release — all hB(s-2) reads are drained (in-block
                // vmcnt) before the barrier above; publish now, not at B_end.
                if (tid == 0) stu32(prog + wg * 32, (u32)(s + 1));
                #pragma unroll
                for (int fc = 0; fc < 6; ++fc) {
                    const int koff = ks * 192 + fc * 32 + quad * 8;
                    bf16x8 f0 = *(const bf16x8*)(actb + nl * ASTR_B + koff * 2);
                    bf16x8 f1 = *(const bf16x8*)(actb + (16 + nl) * ASTR_B + koff * 2);
                    acc0 = __builtin_amdgcn_mfma_f32_16x16x32_bf16(f0, bfr[fc], acc0, 0, 0, 0);
                    acc1 = __builtin_amdgcn_mfma_f32_16x16x32_bf16(f1, bfr[fc], acc1, 0, 0, 0);
                }
                __syncthreads();
            }

            // ---- C tiles -> red (padded; act dead) ----
            // D layout: col n = lane&15, row m = quad*4 + reg.
            *(f32x4*)(red + (size_t)((nt * 2 + 0) * 4 + ks) * RSLAB + nl * RROW + quad * 4) = acc0;
            *(f32x4*)(red + (size_t)((nt * 2 + 1) * 4 + ks) * RSLAB + nl * RROW + quad * 4) = acc1;
            __syncthreads();

            if (role == 2) {
                const int r2 = tid >> 5, bb = tid & 31;
                const int mtr = bb >> 4, mr = bb & 15;
                const int nt0 = r2 >> 4, nr0 = r2 & 15;
                const int nt1 = (r2 + 32) >> 4, nr1 = (r2 + 32) & 15;
                float s0 = 0.f, s1 = 0.f;
                #pragma unroll
                for (int k2 = 0; k2 < 4; ++k2) {
                    s0 += red[(size_t)((nt0 * 2 + mtr) * 4 + k2) * RSLAB + nr0 * RROW + mr];
                    s1 += red[(size_t)((nt1 * 2 + mtr) * 4 + k2) * RSLAB + nr1 * RROW + mr];
                }
                const int v = s - 2;
                float* o = out + ((size_t)bb * Tt + v) * OUTF + obase;
                o[r2]      = s0 + bl0;
                o[32 + r2] = s1 + bl1;
            } else if (tid < 256) {
                // ---- fused K-reduce + gates + direct packed h store ----
                const int jj = tid >> 5, b2 = tid & 31;
                const int mt = b2 >> 4, mr = b2 & 15;
                const int j0 = 2 * jj, j1 = 2 * jj + 1;
                float p0a=0,p1a=0,p2a=0,p3a=0, p0b=0,p1b=0,p2b=0,p3b=0;
                #pragma unroll
                for (int k2 = 0; k2 < 4; ++k2) {
                    p0a += red[(size_t)((0 * 2 + mt) * 4 + k2) * RSLAB + j0 * RROW + mr];
                    p1a += red[(size_t)((1 * 2 + mt) * 4 + k2) * RSLAB + j0 * RROW + mr];
                    p2a += red[(size_t)((2 * 2 + mt) * 4 + k2) * RSLAB + j0 * RROW + mr];
                    p3a += red[(size_t)((3 * 2 + mt) * 4 + k2) * RSLAB + j0 * RROW + mr];
                    p0b += red[(size_t)((0 * 2 + mt) * 4 + k2) * RSLAB + j1 * RROW + mr];
                    p1b += red[(size_t)((1 * 2 + mt) * 4 + k2) * RSLAB + j1 * RROW + mr];
                    p2b += red[(size_t)((2 * 2 + mt) * 4 + k2) * RSLAB + j1 * RROW + mr];
                    p3b += red[(size_t)((3 * 2 + mt) * 4 + k2) * RSLAB + j1 * RROW + mr];
                }
                const float ig0 = sigf(ba0 + p0a), fg0 = sigf(ba1 + p1a);
                const float gv0 = tanhfast(ba2 + p2a), og0 = sigf(ba3 + p3a);
                creg0 = fg0 * creg0 + ig0 * gv0;
                const float h0 = og0 * tanhfast(creg0);
                const float ig1 = sigf(bb0 + p0b), fg1 = sigf(bb1 + p1b);
                const float gv1 = tanhfast(bb2 + p2b), og1 = sigf(bb3 + p3b);
                creg1 = fg1 * creg1 + ig1 * gv1;
                const float h1 = og1 * tanhfast(creg1);
                u16* dst = (role == 0) ? (hA + (size_t)par_wA * HPS)
                                       : (hB + (size_t)par_wB * HPS);
                st32ws(dst + b2 * 768 + jbase + j0, (u32)f2bf(h0) | ((u32)f2bf(h1) << 16));
            }
        }

        // ---- publish progress (barrier drains all stores first) ----
        __syncthreads();
        if (tid == 0) stu32(prog + wg * 32, (u32)(s + 1));
    }
}

extern "C" void kernel_launch(void* const* d_in, const int* in_sizes, int n_in,
                              void* d_out, int out_size, void* d_ws, size_t ws_size,
                              hipStream_t stream)
{
    const float* x    = (const float*)d_in[0];
    const float* Wih0 = (const float*)d_in[1];
    const float* Whh0 = (const float*)d_in[2];
    const float* bih0 = (const float*)d_in[3];
    const float* bhh0 = (const float*)d_in[4];
    const float* Wih1 = (const float*)d_in[5];
    const float* Whh1 = (const float*)d_in[6];
    const float* bih1 = (const float*)d_in[7];
    const float* bhh1 = (const float*)d_in[8];
    const float* Wlin = (const float*)d_in[9];
    const float* blin = (const float*)d_in[10];
    float* out = (float*)d_out;
    char*  ws  = (char*)d_ws;   // uses WS_BYTES = 304 KB

    hipLaunchKernelGGL(prologue, dim3(304), dim3(256), 0, stream, ws);
    hipLaunchKernelGGL(lstm_persist, dim3(NWG), dim3(NTHR), 0, stream,
                       x, Wih0, Whh0, bih0, bhh0,
                       Wih1, Whh1, bih1, bhh1,
                       Wlin, blin, out, ws);
}